// Round 1
// 660.217 us; speedup vs baseline: 3.0097x; 3.0097x over previous
//
#include <hip/hip_runtime.h>

#define BB 8
#define CC 3
#define HH 512
#define WW 512
#define OO 64
#define KK 9

__global__ __launch_bounds__(256, 4) void fused_deform_kernel(
    const float* __restrict__ x,
    const float* __restrict__ w_simple,
    const float* __restrict__ w_off,
    const float* __restrict__ b_off,
    const float* __restrict__ w_mask,
    const float* __restrict__ b_mask,
    float* __restrict__ out)
{
    // Weights staged to LDS, each row padded 27 -> 28 floats so dots run as 7x float4.
    __shared__ __align__(16) float s_woff[18 * 28];
    __shared__ __align__(16) float s_wmsk[9 * 28];
    __shared__ __align__(16) float s_w[64 * 28];
    __shared__ float s_boff[18];
    __shared__ float s_bmsk[9];

    const int tid = threadIdx.x;
    for (int t = tid; t < 18 * 28; t += 256) { int j = t / 28, i = t % 28; s_woff[t] = (i < 27) ? w_off[j * 27 + i] : 0.f; }
    for (int t = tid; t < 9 * 28; t += 256)  { int j = t / 28, i = t % 28; s_wmsk[t] = (i < 27) ? w_mask[j * 27 + i] : 0.f; }
    for (int t = tid; t < 64 * 28; t += 256) { int j = t / 28, i = t % 28; s_w[t]    = (i < 27) ? w_simple[j * 27 + i] : 0.f; }
    if (tid < 18) s_boff[tid] = b_off[tid];
    if (tid < 9)  s_bmsk[tid] = b_mask[tid];
    __syncthreads();

    // XCD swizzle: 8192 blocks round-robin over 8 XCDs; remap so XCD i owns
    // blocks [i*1024, (i+1)*1024) == exactly batch image b=i (3 MB of x -> fits 4 MB L2).
    const int bid = blockIdx.x;
    const int nbid = (bid & 7) * 1024 + (bid >> 3);

    const int idx = nbid * 256 + tid;
    const int w = idx & (WW - 1);
    const int h = (idx >> 9) & (HH - 1);
    const int b = idx >> 18;

    const float* xb = x + (size_t)b * CC * HH * WW;

    // ---- 3x3 neighborhood of x (zero-padded), shared by offset & mask convs ----
    float nb[28];
    #pragma unroll
    for (int c = 0; c < CC; ++c) {
        const float* xc = xb + c * HH * WW;
        #pragma unroll
        for (int i = 0; i < 9; ++i) {
            int yy = h - 1 + i / 3;
            int xx = w - 1 + i % 3;
            float v = 0.f;
            if ((unsigned)yy < (unsigned)HH && (unsigned)xx < (unsigned)WW)
                v = xc[yy * WW + xx];
            nb[c * 9 + i] = v;
        }
    }
    nb[27] = 0.f;

    // ---- offset conv (18 ch) ----
    float offv[18];
    #pragma unroll
    for (int j = 0; j < 18; ++j) {
        float acc = s_boff[j];
        const float4* wp = (const float4*)(s_woff + j * 28);
        #pragma unroll
        for (int q = 0; q < 7; ++q) {
            float4 wq = wp[q];
            acc = fmaf(wq.x, nb[q * 4 + 0], acc);
            acc = fmaf(wq.y, nb[q * 4 + 1], acc);
            acc = fmaf(wq.z, nb[q * 4 + 2], acc);
            acc = fmaf(wq.w, nb[q * 4 + 3], acc);
        }
        offv[j] = acc;
    }

    // ---- mask conv (9 ch) + sigmoid ----
    float mval[9];
    #pragma unroll
    for (int j = 0; j < 9; ++j) {
        float acc = s_bmsk[j];
        const float4* wp = (const float4*)(s_wmsk + j * 28);
        #pragma unroll
        for (int q = 0; q < 7; ++q) {
            float4 wq = wp[q];
            acc = fmaf(wq.x, nb[q * 4 + 0], acc);
            acc = fmaf(wq.y, nb[q * 4 + 1], acc);
            acc = fmaf(wq.z, nb[q * 4 + 2], acc);
            acc = fmaf(wq.w, nb[q * 4 + 3], acc);
        }
        mval[j] = 1.f / (1.f + __expf(-acc));
    }

    // ---- deformable bilinear sampling ----
    // Branchless: clamp the 4 corner addresses, fold (valid * mask) into the 4
    // bilinear weights, then 12 unconditional loads per k. Matches reference
    // semantics (invalid corners contribute 0).
    float vv[28];
    vv[27] = 0.f;
    #pragma unroll
    for (int k = 0; k < 9; ++k) {
        float py = (float)(h - 1 + k / 3) + offv[2 * k + 0];
        float px = (float)(w - 1 + k % 3) + offv[2 * k + 1];
        float y0f = floorf(py);
        float x0f = floorf(px);
        float ty = py - y0f;
        float tx = px - x0f;
        int y0 = (int)y0f;
        int x0 = (int)x0f;
        int y1 = y0 + 1;
        int x1 = x0 + 1;
        bool vy0 = (unsigned)y0 < (unsigned)HH;
        bool vy1 = (unsigned)y1 < (unsigned)HH;
        bool vx0 = (unsigned)x0 < (unsigned)WW;
        bool vx1 = (unsigned)x1 < (unsigned)WW;
        int yc0 = min(max(y0, 0), HH - 1);
        int yc1 = min(max(y1, 0), HH - 1);
        int xc0 = min(max(x0, 0), WW - 1);
        int xc1 = min(max(x1, 0), WW - 1);
        int l00 = yc0 * WW + xc0;
        int l01 = yc0 * WW + xc1;
        int l10 = yc1 * WW + xc0;
        int l11 = yc1 * WW + xc1;
        float mk = mval[k];
        float w00 = (vy0 && vx0) ? (1.f - ty) * (1.f - tx) * mk : 0.f;
        float w01 = (vy0 && vx1) ? (1.f - ty) * tx * mk : 0.f;
        float w10 = (vy1 && vx0) ? ty * (1.f - tx) * mk : 0.f;
        float w11 = (vy1 && vx1) ? ty * tx * mk : 0.f;
        #pragma unroll
        for (int c = 0; c < CC; ++c) {
            const float* xc = xb + c * HH * WW;
            float s;
            s = w00 * xc[l00];
            s = fmaf(w01, xc[l01], s);
            s = fmaf(w10, xc[l10], s);
            s = fmaf(w11, xc[l11], s);
            vv[c * 9 + k] = s;
        }
    }

    // ---- einsum: out[b,o,h,w] = sum_{c,k} w_simple[o,c,k] * v[c,k] ----
    // Non-temporal stores: out (537 MB) is never re-read; keep it out of L2
    // so x stays resident per-XCD.
    const size_t obase = (size_t)b * OO * HH * WW + (size_t)h * WW + w;
    #pragma unroll 4
    for (int o = 0; o < OO; ++o) {
        float acc = 0.f;
        const float4* wp = (const float4*)(s_w + o * 28);
        #pragma unroll
        for (int q = 0; q < 7; ++q) {
            float4 wq = wp[q];
            acc = fmaf(wq.x, vv[q * 4 + 0], acc);
            acc = fmaf(wq.y, vv[q * 4 + 1], acc);
            acc = fmaf(wq.z, vv[q * 4 + 2], acc);
            acc = fmaf(wq.w, vv[q * 4 + 3], acc);
        }
        __builtin_nontemporal_store(acc, &out[obase + (size_t)o * HH * WW]);
    }
}

extern "C" void kernel_launch(void* const* d_in, const int* in_sizes, int n_in,
                              void* d_out, int out_size, void* d_ws, size_t ws_size,
                              hipStream_t stream) {
    const float* x        = (const float*)d_in[0];
    const float* w_simple = (const float*)d_in[1];
    const float* w_off    = (const float*)d_in[2];
    const float* b_off    = (const float*)d_in[3];
    const float* w_mask   = (const float*)d_in[4];
    const float* b_mask   = (const float*)d_in[5];
    float* out = (float*)d_out;

    const int total = BB * HH * WW;           // 2,097,152 pixels
    const int block = 256;
    const int grid = total / block;           // 8192 blocks
    fused_deform_kernel<<<grid, block, 0, stream>>>(x, w_simple, w_off, b_off, w_mask, b_mask, out);
}